// Round 9
// baseline (205.166 us; speedup 1.0000x reference)
//
#include <hip/hip_runtime.h>
#include <math.h>

#define T_SEQ 4096
#define NBATCH 4
#define NEMBD 1024
#define HS 64
#define BT (NBATCH * T_SEQ)   // 16384

typedef float f32x4 __attribute__((ext_vector_type(4)));
typedef short s8v  __attribute__((ext_vector_type(8)));   // 8 x bf16 bits
typedef short s4v  __attribute__((ext_vector_type(4)));   // 4 x bf16 bits

__device__ __forceinline__ short f2b_rne(float f) {
    union { float f; unsigned u; } v; v.f = f;
    unsigned r = v.u + 0x7fffu + ((v.u >> 16) & 1u);
    return (short)(r >> 16);
}
// pack 2 fp32 -> 2 bf16 (truncate) in one v_perm
__device__ __forceinline__ unsigned pk2(float lo, float hi) {
    return __builtin_amdgcn_perm(__float_as_uint(hi), __float_as_uint(lo), 0x07060302u);
}

// ---------------------------------------------------------------------------
// Kernel 0a: linear cast x fp32 -> xb bf16 (HBM-friendly streaming).
// ---------------------------------------------------------------------------
__global__ __launch_bounds__(256) void xcast_kernel(
        const float* __restrict__ x, short* __restrict__ xb) {
    size_t i = ((size_t)blockIdx.x * 256 + threadIdx.x) * 16;
    float4 a = *(const float4*)(x + i);
    float4 b = *(const float4*)(x + i + 4);
    float4 c = *(const float4*)(x + i + 8);
    float4 d = *(const float4*)(x + i + 12);
    union { s8v v; unsigned u[4]; } v0, v1;
    v0.u[0] = pk2(a.x, a.y); v0.u[1] = pk2(a.z, a.w);
    v0.u[2] = pk2(b.x, b.y); v0.u[3] = pk2(b.z, b.w);
    v1.u[0] = pk2(c.x, c.y); v1.u[1] = pk2(c.z, c.w);
    v1.u[2] = pk2(d.x, d.y); v1.u[3] = pk2(d.z, d.w);
    *(s8v*)(xb + i) = v0.v;
    *(s8v*)(xb + i + 8) = v1.v;
}

// Kernel 0b (fallback if ws too small): linear touch of x to warm L3.
__global__ __launch_bounds__(256) void xtouch_kernel(
        const float* __restrict__ x, float* __restrict__ sink) {
    const float4* p = (const float4*)x;
    float s = 0.f;
    #pragma unroll
    for (int it = 0; it < 8; it++) {
        float4 v = p[(size_t)blockIdx.x * 2048 + it * 256 + threadIdx.x];
        s += v.x + v.y + v.z + v.w;
    }
    if (s == 1.0e38f) sink[0] = s;
}

// ---------------------------------------------------------------------------
// Kernel 1: W{q,k,v} [1024x64] fp32 -> Wt[192][1024] bf16 transposed.
// Softmax scale C^-0.5 * log2(e) folded into Wq.
// ---------------------------------------------------------------------------
__global__ __launch_bounds__(256) void wtrans_kernel(
        const float* __restrict__ Wq, const float* __restrict__ Wk,
        const float* __restrict__ Wv, short* __restrict__ Wt) {
    int e = blockIdx.x * 256 + threadIdx.x;
    int col = e & 63, k = (e >> 6) & 1023, mat = e >> 16;
    const float* W = (mat == 0) ? Wq : ((mat == 1) ? Wk : Wv);
    float scale = (mat == 0) ? 0.0450842298f : 1.0f;   // 2^-5 * log2(e)
    Wt[(size_t)(mat * 64 + col) * 1024 + k] = f2b_rne(W[k * 64 + col] * scale);
}

// ---------------------------------------------------------------------------
// Kernel 2: projections v3 (unchanged from R7).
// ---------------------------------------------------------------------------
template<bool SRC_BF16>
__global__ __launch_bounds__(512) void proj_kernel(
        const void* __restrict__ xsrc, const short* __restrict__ Wt,
        short* __restrict__ QKV) {
    __shared__ short xs[32 * 72];
    __shared__ short wsh[192 * 72];
    int tid = threadIdx.x;
    int w = tid >> 6, l = tid & 63, quad = l >> 4, c16 = l & 15;
    int rt = w >> 2, cg = w & 3;
    int row0 = blockIdx.x * 32;
    short* VpT = QKV + 2 * (size_t)BT * HS;   // tiled [b][kt][64 d][64 key]

    const short* xb = (const short*)xsrc;
    const float* xf = (const float*)xsrc;
    int xrow_b = tid >> 3,  xc8 = (tid & 7) * 8;
    int xrow_f = tid >> 4,  xc4 = (tid & 15) * 4;

    s8v  wreg[3];
    s8v  xreg_b;
    float4 xreg_f;
    #pragma unroll
    for (int i = 0; i < 3; i++) {
        int c = tid + 512 * i;
        wreg[i] = *(const s8v*)(Wt + (size_t)(c >> 3) * 1024 + ((c & 7) * 8));
    }
    if (SRC_BF16) {
        if (tid < 256) xreg_b = *(const s8v*)(xb + (size_t)(row0 + xrow_b) * 1024 + xc8);
    } else {
        xreg_f = *(const float4*)(xf + (size_t)(row0 + xrow_f) * 1024 + xc4);
    }

    f32x4 acc[3] = {};
    for (int ko = 0; ko < NEMBD; ko += 64) {
        #pragma unroll
        for (int i = 0; i < 3; i++) {
            int c = tid + 512 * i;
            *(s8v*)(wsh + (c >> 3) * 72 + ((c & 7) * 8)) = wreg[i];
        }
        if (SRC_BF16) {
            if (tid < 256) *(s8v*)(xs + xrow_b * 72 + xc8) = xreg_b;
        } else {
            union { s4v v; unsigned u[2]; } pkv;
            pkv.u[0] = pk2(xreg_f.x, xreg_f.y);
            pkv.u[1] = pk2(xreg_f.z, xreg_f.w);
            *(s4v*)(xs + xrow_f * 72 + xc4) = pkv.v;
        }
        __syncthreads();
        {
            int kn = (ko + 64 < NEMBD) ? (ko + 64) : 0;
            #pragma unroll
            for (int i = 0; i < 3; i++) {
                int c = tid + 512 * i;
                wreg[i] = *(const s8v*)(Wt + (size_t)(c >> 3) * 1024 + kn + ((c & 7) * 8));
            }
            if (SRC_BF16) {
                if (tid < 256) xreg_b = *(const s8v*)(xb + (size_t)(row0 + xrow_b) * 1024 + kn + xc8);
            } else {
                xreg_f = *(const float4*)(xf + (size_t)(row0 + xrow_f) * 1024 + kn + xc4);
            }
        }
        #pragma unroll
        for (int ks = 0; ks < 2; ks++) {
            s8v a = *(const s8v*)(xs + (rt * 16 + c16) * 72 + ks * 32 + quad * 8);
            #pragma unroll
            for (int j = 0; j < 3; j++) {
                s8v b = *(const s8v*)(wsh + (cg * 48 + j * 16 + c16) * 72 + ks * 32 + quad * 8);
                acc[j] = __builtin_amdgcn_mfma_f32_16x16x32_bf16(a, b, acc[j], 0, 0, 0);
            }
        }
        __syncthreads();
    }
    #pragma unroll
    for (int j = 0; j < 3; j++) {
        int g = cg * 48 + j * 16 + c16;
        int mat = g >> 6, h = g & 63;
        if (mat < 2) {
            #pragma unroll
            for (int r = 0; r < 4; r++) {
                int row = row0 + rt * 16 + quad * 4 + r;
                QKV[(size_t)mat * BT * HS + (size_t)row * HS + h] = f2b_rne(acc[j][r]);
            }
        } else {
            int tg = row0 + rt * 16 + quad * 4;
            int b = tg >> 12, t = tg & 4095;
            size_t base = (((size_t)((b * 64 + (t >> 6)) * 64 + h)) << 6) + (t & 63);
            s4v pv;
            #pragma unroll
            for (int r = 0; r < 4; r++) pv[r] = f2b_rne(acc[j][r]);
            *(s4v*)(VpT + base) = pv;
        }
    }
}

// ---------------------------------------------------------------------------
// Kernel 3: causal flash attention.  R9 changes:
//  (a) block remap: batch b = (bi&7)>>1 pins each batch's 1MB K/V working
//      set to one XCD pair's L2 (was: all 4 batches thrash every 4MB L2);
//      jt chosen so CU-paired blocks (bi, bi+256) have nkt summing ~const
//      (R8 pairing had a 1.5x CU imbalance: work/CU = 97-(i>>2)).
//  (b) cross-tile K prefetch: kf for kt+8 reloaded right after the V loads,
//      in flight across softmax+P+PV -> next S-wait mostly hidden.
// ---------------------------------------------------------------------------
__global__ __launch_bounds__(512, 4) void attn_kernel(
        const short* __restrict__ QKV, float* __restrict__ out) {
    __shared__ float smem[9216];   // 36 KB: P regions; epilogue overlays
    short* Ps = (short*)smem;

    int tid = threadIdx.x;
    int w = tid >> 6, l = tid & 63, quad = l >> 4, c16 = l & 15;
    int bi = blockIdx.x;
    int b  = (bi & 7) >> 1;                 // XCD-affine batch
    int r8 = bi >> 3;                       // 0..63
    int p  = bi & 1;
    int jt = (r8 < 32) ? (127 - (2 * r8 + p)) : (2 * (r8 - 32) + p);
    int q0 = jt * 32;

    const short* Qp  = QKV;
    const short* Kp  = QKV + (size_t)BT * HS;
    const short* VpT = QKV + 2 * (size_t)BT * HS;   // tiled
    size_t bT = (size_t)b * T_SEQ;

    s8v qf[2][2];
    #pragma unroll
    for (int qt = 0; qt < 2; qt++)
        #pragma unroll
        for (int h = 0; h < 2; h++)
            qf[qt][h] = *(const s8v*)(Qp + (bT + q0 + qt * 16 + c16) * HS + h * 32 + quad * 8);

    f32x4 o[2][4] = {};
    float lsum[2] = {0.f, 0.f};
    int nkt = (q0 >> 6) + 1;
    short* Pw[2] = { Ps + (w * 2) * 1152, Ps + (w * 2 + 1) * 1152 };
    const short* kbase = Kp + (bT + c16) * HS + quad * 8;
    const short* vbase = VpT + (((size_t)((b * 64) * 64 + c16)) << 6) + quad * 8;

    // prefetch K frags for first tile
    s8v kf[4][2];
    if (w < nkt) {
        #pragma unroll
        for (int nt = 0; nt < 4; nt++) {
            const short* kr = kbase + (size_t)(w * 64 + nt * 16) * HS;
            kf[nt][0] = *(const s8v*)kr;
            kf[nt][1] = *(const s8v*)(kr + 32);
        }
    }

    for (int kt = w; kt < nkt; kt += 8) {
        int kb = kt * 64;
        bool last = (kt == nkt - 1);

        // ---- S^T = K * Q^T (kf prefetched) ----
        f32x4 st[2][4];
        #pragma unroll
        for (int nt = 0; nt < 4; nt++) {
            f32x4 z0 = {0.f, 0.f, 0.f, 0.f}, z1 = {0.f, 0.f, 0.f, 0.f};
            z0 = __builtin_amdgcn_mfma_f32_16x16x32_bf16(kf[nt][0], qf[0][0], z0, 0, 0, 0);
            z0 = __builtin_amdgcn_mfma_f32_16x16x32_bf16(kf[nt][1], qf[0][1], z0, 0, 0, 0);
            z1 = __builtin_amdgcn_mfma_f32_16x16x32_bf16(kf[nt][0], qf[1][0], z1, 0, 0, 0);
            z1 = __builtin_amdgcn_mfma_f32_16x16x32_bf16(kf[nt][1], qf[1][1], z1, 0, 0, 0);
            st[0][nt] = z0; st[1][nt] = z1;
        }
        // ---- issue ALL V loads + NEXT tile's K loads (hidden by softmax+PV) ----
        s8v vf[4][2];
        #pragma unroll
        for (int nt = 0; nt < 4; nt++) {
            const short* vr = vbase + (((size_t)(kt * 64 + nt * 16)) << 6);
            vf[nt][0] = *(const s8v*)vr;
            vf[nt][1] = *(const s8v*)(vr + 32);
        }
        if (kt + 8 < nkt) {
            #pragma unroll
            for (int nt = 0; nt < 4; nt++) {
                const short* kr = kbase + (size_t)((kt + 8) * 64 + nt * 16) * HS;
                kf[nt][0] = *(const s8v*)kr;
                kf[nt][1] = *(const s8v*)(kr + 32);
            }
        }
        // ---- exp2, diag mask, lsum, pack P -> LDS ----
        #pragma unroll
        for (int qt = 0; qt < 2; qt++) {
            int qrow = q0 + qt * 16 + c16;
            #pragma unroll
            for (int nt = 0; nt < 4; nt++) {
                float pr[4];
                #pragma unroll
                for (int rr = 0; rr < 4; rr++) {
                    float v = st[qt][nt][rr];
                    if (last && (kb + nt * 16 + quad * 4 + rr > qrow)) v = -30000.f;
                    pr[rr] = __builtin_amdgcn_exp2f(v);
                    lsum[qt] += pr[rr];
                }
                union { s4v v; unsigned u[2]; } pkv;
                pkv.u[0] = pk2(pr[0], pr[1]); pkv.u[1] = pk2(pr[2], pr[3]);
                *(s4v*)(Pw[qt] + c16 * 72 + nt * 16 + quad * 4) = pkv.v;
            }
        }
        // ---- P A-frags from LDS; PV MFMAs ----
        s8v pa[2][2];
        #pragma unroll
        for (int qt = 0; qt < 2; qt++) {
            pa[qt][0] = *(const s8v*)(Pw[qt] + c16 * 72 + quad * 8);
            pa[qt][1] = *(const s8v*)(Pw[qt] + c16 * 72 + quad * 8 + 32);
        }
        #pragma unroll
        for (int nt = 0; nt < 4; nt++)
            #pragma unroll
            for (int qt = 0; qt < 2; qt++) {
                o[qt][nt] = __builtin_amdgcn_mfma_f32_16x16x32_bf16(pa[qt][0], vf[nt][0], o[qt][nt], 0, 0, 0);
                o[qt][nt] = __builtin_amdgcn_mfma_f32_16x16x32_bf16(pa[qt][1], vf[nt][1], o[qt][nt], 0, 0, 0);
            }
    }

    #pragma unroll
    for (int qt = 0; qt < 2; qt++) {
        lsum[qt] += __shfl_xor(lsum[qt], 16);
        lsum[qt] += __shfl_xor(lsum[qt], 32);
    }

    // two-phase per-lane merge (R5 fix)
    #pragma unroll
    for (int qt = 0; qt < 2; qt++) {
        __syncthreads();
        #pragma unroll
        for (int nt = 0; nt < 4; nt++)
            *(f32x4*)(smem + ((w * 4 + nt) * 64 + l) * 4) = o[qt][nt];
        if (l < 16) smem[8192 + w * 16 + l] = lsum[qt];
        __syncthreads();
        if (w < 4) {
            f32x4 os = {0.f, 0.f, 0.f, 0.f}, ls = {0.f, 0.f, 0.f, 0.f};
            #pragma unroll
            for (int s = 0; s < 8; s++) {
                os += *(const f32x4*)(smem + ((s * 4 + w) * 64 + l) * 4);
                ls += *(const f32x4*)(smem + 8192 + s * 16 + quad * 4);
            }
            #pragma unroll
            for (int rr = 0; rr < 4; rr++)
                out[(bT + q0 + qt * 16 + quad * 4 + rr) * HS + w * 16 + c16] = os[rr] / ls[rr];
        }
    }
}

// ---------------------------------------------------------------------------
extern "C" void kernel_launch(void* const* d_in, const int* in_sizes, int n_in,
                              void* d_out, int out_size, void* d_ws, size_t ws_size,
                              hipStream_t stream) {
    const float* x  = (const float*)d_in[0];
    const float* Wq = (const float*)d_in[1];
    const float* Wk = (const float*)d_in[2];
    const float* Wv = (const float*)d_in[3];
    float* out = (float*)d_out;

    short* QKV = (short*)d_ws;
    short* Wt  = QKV + (size_t)3 * BT * HS;
    short* xb  = Wt + (size_t)192 * 1024;
    size_t need = ((size_t)3 * BT * HS + (size_t)192 * 1024 + (size_t)BT * NEMBD) * 2;

    wtrans_kernel<<<768, 256, 0, stream>>>(Wq, Wk, Wv, Wt);
    if (ws_size >= need) {
        xcast_kernel<<<4096, 256, 0, stream>>>(x, xb);
        proj_kernel<true><<<BT / 32, 512, 0, stream>>>(xb, Wt, QKV);
    } else {
        xtouch_kernel<<<2048, 256, 0, stream>>>(x, (float*)d_ws);
        proj_kernel<false><<<BT / 32, 512, 0, stream>>>(x, Wt, QKV);
    }
    attn_kernel<<<512, 512, 0, stream>>>(QKV, out);
}

// Round 10
// 160.526 us; speedup vs baseline: 1.2781x; 1.2781x over previous
//
#include <hip/hip_runtime.h>
#include <math.h>

#define T_SEQ 4096
#define NBATCH 4
#define NEMBD 1024
#define HS 64
#define BT (NBATCH * T_SEQ)   // 16384

typedef float f32x4 __attribute__((ext_vector_type(4)));
typedef short s8v  __attribute__((ext_vector_type(8)));   // 8 x bf16 bits
typedef short s4v  __attribute__((ext_vector_type(4)));   // 4 x bf16 bits

__device__ __forceinline__ short f2b_rne(float f) {
    union { float f; unsigned u; } v; v.f = f;
    unsigned r = v.u + 0x7fffu + ((v.u >> 16) & 1u);
    return (short)(r >> 16);
}
// pack 2 fp32 -> 2 bf16 (truncate) in one v_perm
__device__ __forceinline__ unsigned pk2(float lo, float hi) {
    return __builtin_amdgcn_perm(__float_as_uint(hi), __float_as_uint(lo), 0x07060302u);
}

// ---------------------------------------------------------------------------
// Kernel 0a: linear cast x fp32 -> xb bf16 (HBM-friendly streaming).
// ---------------------------------------------------------------------------
__global__ __launch_bounds__(256) void xcast_kernel(
        const float* __restrict__ x, short* __restrict__ xb) {
    size_t i = ((size_t)blockIdx.x * 256 + threadIdx.x) * 16;
    float4 a = *(const float4*)(x + i);
    float4 b = *(const float4*)(x + i + 4);
    float4 c = *(const float4*)(x + i + 8);
    float4 d = *(const float4*)(x + i + 12);
    union { s8v v; unsigned u[4]; } v0, v1;
    v0.u[0] = pk2(a.x, a.y); v0.u[1] = pk2(a.z, a.w);
    v0.u[2] = pk2(b.x, b.y); v0.u[3] = pk2(b.z, b.w);
    v1.u[0] = pk2(c.x, c.y); v1.u[1] = pk2(c.z, c.w);
    v1.u[2] = pk2(d.x, d.y); v1.u[3] = pk2(d.z, d.w);
    *(s8v*)(xb + i) = v0.v;
    *(s8v*)(xb + i + 8) = v1.v;
}

// Kernel 0b (fallback if ws too small): linear touch of x to warm L3.
__global__ __launch_bounds__(256) void xtouch_kernel(
        const float* __restrict__ x, float* __restrict__ sink) {
    const float4* p = (const float4*)x;
    float s = 0.f;
    #pragma unroll
    for (int it = 0; it < 8; it++) {
        float4 v = p[(size_t)blockIdx.x * 2048 + it * 256 + threadIdx.x];
        s += v.x + v.y + v.z + v.w;
    }
    if (s == 1.0e38f) sink[0] = s;
}

// ---------------------------------------------------------------------------
// Kernel 1: W{q,k,v} [1024x64] fp32 -> Wt[192][1024] bf16 transposed.
// Softmax scale C^-0.5 * log2(e) folded into Wq.
// ---------------------------------------------------------------------------
__global__ __launch_bounds__(256) void wtrans_kernel(
        const float* __restrict__ Wq, const float* __restrict__ Wk,
        const float* __restrict__ Wv, short* __restrict__ Wt) {
    int e = blockIdx.x * 256 + threadIdx.x;
    int col = e & 63, k = (e >> 6) & 1023, mat = e >> 16;
    const float* W = (mat == 0) ? Wq : ((mat == 1) ? Wk : Wv);
    float scale = (mat == 0) ? 0.0450842298f : 1.0f;   // 2^-5 * log2(e)
    Wt[(size_t)(mat * 64 + col) * 1024 + k] = f2b_rne(W[k * 64 + col] * scale);
}

// ---------------------------------------------------------------------------
// Kernel 2: projections v3 (unchanged from R7).
// ---------------------------------------------------------------------------
template<bool SRC_BF16>
__global__ __launch_bounds__(512) void proj_kernel(
        const void* __restrict__ xsrc, const short* __restrict__ Wt,
        short* __restrict__ QKV) {
    __shared__ short xs[32 * 72];
    __shared__ short wsh[192 * 72];
    int tid = threadIdx.x;
    int w = tid >> 6, l = tid & 63, quad = l >> 4, c16 = l & 15;
    int rt = w >> 2, cg = w & 3;
    int row0 = blockIdx.x * 32;
    short* VpT = QKV + 2 * (size_t)BT * HS;   // tiled [b][kt][64 d][64 key]

    const short* xb = (const short*)xsrc;
    const float* xf = (const float*)xsrc;
    int xrow_b = tid >> 3,  xc8 = (tid & 7) * 8;
    int xrow_f = tid >> 4,  xc4 = (tid & 15) * 4;

    s8v  wreg[3];
    s8v  xreg_b;
    float4 xreg_f;
    #pragma unroll
    for (int i = 0; i < 3; i++) {
        int c = tid + 512 * i;
        wreg[i] = *(const s8v*)(Wt + (size_t)(c >> 3) * 1024 + ((c & 7) * 8));
    }
    if (SRC_BF16) {
        if (tid < 256) xreg_b = *(const s8v*)(xb + (size_t)(row0 + xrow_b) * 1024 + xc8);
    } else {
        xreg_f = *(const float4*)(xf + (size_t)(row0 + xrow_f) * 1024 + xc4);
    }

    f32x4 acc[3] = {};
    for (int ko = 0; ko < NEMBD; ko += 64) {
        #pragma unroll
        for (int i = 0; i < 3; i++) {
            int c = tid + 512 * i;
            *(s8v*)(wsh + (c >> 3) * 72 + ((c & 7) * 8)) = wreg[i];
        }
        if (SRC_BF16) {
            if (tid < 256) *(s8v*)(xs + xrow_b * 72 + xc8) = xreg_b;
        } else {
            union { s4v v; unsigned u[2]; } pkv;
            pkv.u[0] = pk2(xreg_f.x, xreg_f.y);
            pkv.u[1] = pk2(xreg_f.z, xreg_f.w);
            *(s4v*)(xs + xrow_f * 72 + xc4) = pkv.v;
        }
        __syncthreads();
        {
            int kn = (ko + 64 < NEMBD) ? (ko + 64) : 0;
            #pragma unroll
            for (int i = 0; i < 3; i++) {
                int c = tid + 512 * i;
                wreg[i] = *(const s8v*)(Wt + (size_t)(c >> 3) * 1024 + kn + ((c & 7) * 8));
            }
            if (SRC_BF16) {
                if (tid < 256) xreg_b = *(const s8v*)(xb + (size_t)(row0 + xrow_b) * 1024 + kn + xc8);
            } else {
                xreg_f = *(const float4*)(xf + (size_t)(row0 + xrow_f) * 1024 + kn + xc4);
            }
        }
        #pragma unroll
        for (int ks = 0; ks < 2; ks++) {
            s8v a = *(const s8v*)(xs + (rt * 16 + c16) * 72 + ks * 32 + quad * 8);
            #pragma unroll
            for (int j = 0; j < 3; j++) {
                s8v b = *(const s8v*)(wsh + (cg * 48 + j * 16 + c16) * 72 + ks * 32 + quad * 8);
                acc[j] = __builtin_amdgcn_mfma_f32_16x16x32_bf16(a, b, acc[j], 0, 0, 0);
            }
        }
        __syncthreads();
    }
    #pragma unroll
    for (int j = 0; j < 3; j++) {
        int g = cg * 48 + j * 16 + c16;
        int mat = g >> 6, h = g & 63;
        if (mat < 2) {
            #pragma unroll
            for (int r = 0; r < 4; r++) {
                int row = row0 + rt * 16 + quad * 4 + r;
                QKV[(size_t)mat * BT * HS + (size_t)row * HS + h] = f2b_rne(acc[j][r]);
            }
        } else {
            int tg = row0 + rt * 16 + quad * 4;
            int b = tg >> 12, t = tg & 4095;
            size_t base = (((size_t)((b * 64 + (t >> 6)) * 64 + h)) << 6) + (t & 63);
            s4v pv;
            #pragma unroll
            for (int r = 0; r < 4; r++) pv[r] = f2b_rne(acc[j][r]);
            *(s4v*)(VpT + base) = pv;
        }
    }
}

// ---------------------------------------------------------------------------
// Kernel 3: causal flash attention.  R10 = R8 phase structure (K loads at
// loop top -> one wait; V loads after S-MFMAs, hidden by softmax; NO
// cross-tile K prefetch — R9's prefetch pushed peak regs ~160 > 128 cap and
// spilled 198MB/dispatch to scratch) + R9's balanced XCD-affine remap
// (batch pinned to an XCD pair; CU-paired blocks have nkt summing ~const,
// fixing R8's 1.5x CU imbalance).
// ---------------------------------------------------------------------------
__global__ __launch_bounds__(512, 4) void attn_kernel(
        const short* __restrict__ QKV, float* __restrict__ out) {
    __shared__ float smem[9216];   // 36 KB: P regions; epilogue overlays
    short* Ps = (short*)smem;

    int tid = threadIdx.x;
    int w = tid >> 6, l = tid & 63, quad = l >> 4, c16 = l & 15;
    int bi = blockIdx.x;
    int b  = (bi & 7) >> 1;                 // XCD-affine batch
    int r8 = bi >> 3;                       // 0..63
    int p  = bi & 1;
    int jt = (r8 < 32) ? (127 - (2 * r8 + p)) : (2 * (r8 - 32) + p);
    int q0 = jt * 32;

    const short* Qp  = QKV;
    const short* Kp  = QKV + (size_t)BT * HS;
    const short* VpT = QKV + 2 * (size_t)BT * HS;   // tiled
    size_t bT = (size_t)b * T_SEQ;

    s8v qf[2][2];
    #pragma unroll
    for (int qt = 0; qt < 2; qt++)
        #pragma unroll
        for (int h = 0; h < 2; h++)
            qf[qt][h] = *(const s8v*)(Qp + (bT + q0 + qt * 16 + c16) * HS + h * 32 + quad * 8);

    f32x4 o[2][4] = {};
    float lsum[2] = {0.f, 0.f};
    int nkt = (q0 >> 6) + 1;
    short* Pw[2] = { Ps + (w * 2) * 1152, Ps + (w * 2 + 1) * 1152 };
    const short* kbase = Kp + (bT + c16) * HS + quad * 8;
    const short* vbase = VpT + (((size_t)((b * 64) * 64 + c16)) << 6) + quad * 8;

    for (int kt = w; kt < nkt; kt += 8) {
        int kb = kt * 64;
        bool last = (kt == nkt - 1);

        // ---- phase 1: issue ALL K fragment loads (8 x b128, one wait) ----
        s8v kf[4][2];
        #pragma unroll
        for (int nt = 0; nt < 4; nt++) {
            const short* kr = kbase + (size_t)(kb + nt * 16) * HS;
            kf[nt][0] = *(const s8v*)kr;
            kf[nt][1] = *(const s8v*)(kr + 32);
        }
        // ---- phase 2: S^T = K * Q^T ----
        f32x4 st[2][4];
        #pragma unroll
        for (int nt = 0; nt < 4; nt++) {
            f32x4 z0 = {0.f, 0.f, 0.f, 0.f}, z1 = {0.f, 0.f, 0.f, 0.f};
            z0 = __builtin_amdgcn_mfma_f32_16x16x32_bf16(kf[nt][0], qf[0][0], z0, 0, 0, 0);
            z0 = __builtin_amdgcn_mfma_f32_16x16x32_bf16(kf[nt][1], qf[0][1], z0, 0, 0, 0);
            z1 = __builtin_amdgcn_mfma_f32_16x16x32_bf16(kf[nt][0], qf[1][0], z1, 0, 0, 0);
            z1 = __builtin_amdgcn_mfma_f32_16x16x32_bf16(kf[nt][1], qf[1][1], z1, 0, 0, 0);
            st[0][nt] = z0; st[1][nt] = z1;
        }
        // ---- phase 3: issue ALL V fragment loads (hidden by softmax) ----
        s8v vf[4][2];
        #pragma unroll
        for (int nt = 0; nt < 4; nt++) {
            const short* vr = vbase + (((size_t)(kt * 64 + nt * 16)) << 6);
            vf[nt][0] = *(const s8v*)vr;
            vf[nt][1] = *(const s8v*)(vr + 32);
        }
        // ---- phase 4: exp2, diag mask, lsum, pack P -> LDS ----
        #pragma unroll
        for (int qt = 0; qt < 2; qt++) {
            int qrow = q0 + qt * 16 + c16;
            #pragma unroll
            for (int nt = 0; nt < 4; nt++) {
                float pr[4];
                #pragma unroll
                for (int rr = 0; rr < 4; rr++) {
                    float v = st[qt][nt][rr];
                    if (last && (kb + nt * 16 + quad * 4 + rr > qrow)) v = -30000.f;
                    pr[rr] = __builtin_amdgcn_exp2f(v);
                    lsum[qt] += pr[rr];
                }
                union { s4v v; unsigned u[2]; } pkv;
                pkv.u[0] = pk2(pr[0], pr[1]); pkv.u[1] = pk2(pr[2], pr[3]);
                *(s4v*)(Pw[qt] + c16 * 72 + nt * 16 + quad * 4) = pkv.v;
            }
        }
        // ---- phase 5: P A-frags from LDS; phase 6: PV MFMAs ----
        s8v pa[2][2];
        #pragma unroll
        for (int qt = 0; qt < 2; qt++) {
            pa[qt][0] = *(const s8v*)(Pw[qt] + c16 * 72 + quad * 8);
            pa[qt][1] = *(const s8v*)(Pw[qt] + c16 * 72 + quad * 8 + 32);
        }
        #pragma unroll
        for (int nt = 0; nt < 4; nt++)
            #pragma unroll
            for (int qt = 0; qt < 2; qt++) {
                o[qt][nt] = __builtin_amdgcn_mfma_f32_16x16x32_bf16(pa[qt][0], vf[nt][0], o[qt][nt], 0, 0, 0);
                o[qt][nt] = __builtin_amdgcn_mfma_f32_16x16x32_bf16(pa[qt][1], vf[nt][1], o[qt][nt], 0, 0, 0);
            }
    }

    #pragma unroll
    for (int qt = 0; qt < 2; qt++) {
        lsum[qt] += __shfl_xor(lsum[qt], 16);
        lsum[qt] += __shfl_xor(lsum[qt], 32);
    }

    // two-phase per-lane merge (R5 fix)
    #pragma unroll
    for (int qt = 0; qt < 2; qt++) {
        __syncthreads();
        #pragma unroll
        for (int nt = 0; nt < 4; nt++)
            *(f32x4*)(smem + ((w * 4 + nt) * 64 + l) * 4) = o[qt][nt];
        if (l < 16) smem[8192 + w * 16 + l] = lsum[qt];
        __syncthreads();
        if (w < 4) {
            f32x4 os = {0.f, 0.f, 0.f, 0.f}, ls = {0.f, 0.f, 0.f, 0.f};
            #pragma unroll
            for (int s = 0; s < 8; s++) {
                os += *(const f32x4*)(smem + ((s * 4 + w) * 64 + l) * 4);
                ls += *(const f32x4*)(smem + 8192 + s * 16 + quad * 4);
            }
            #pragma unroll
            for (int rr = 0; rr < 4; rr++)
                out[(bT + q0 + qt * 16 + quad * 4 + rr) * HS + w * 16 + c16] = os[rr] / ls[rr];
        }
    }
}

// ---------------------------------------------------------------------------
extern "C" void kernel_launch(void* const* d_in, const int* in_sizes, int n_in,
                              void* d_out, int out_size, void* d_ws, size_t ws_size,
                              hipStream_t stream) {
    const float* x  = (const float*)d_in[0];
    const float* Wq = (const float*)d_in[1];
    const float* Wk = (const float*)d_in[2];
    const float* Wv = (const float*)d_in[3];
    float* out = (float*)d_out;

    short* QKV = (short*)d_ws;
    short* Wt  = QKV + (size_t)3 * BT * HS;
    short* xb  = Wt + (size_t)192 * 1024;
    size_t need = ((size_t)3 * BT * HS + (size_t)192 * 1024 + (size_t)BT * NEMBD) * 2;

    wtrans_kernel<<<768, 256, 0, stream>>>(Wq, Wk, Wv, Wt);
    if (ws_size >= need) {
        xcast_kernel<<<4096, 256, 0, stream>>>(x, xb);
        proj_kernel<true><<<BT / 32, 512, 0, stream>>>(xb, Wt, QKV);
    } else {
        xtouch_kernel<<<2048, 256, 0, stream>>>(x, (float*)d_ws);
        proj_kernel<false><<<BT / 32, 512, 0, stream>>>(x, Wt, QKV);
    }
    attn_kernel<<<512, 512, 0, stream>>>(QKV, out);
}